// Round 3
// baseline (67.499 us; speedup 1.0000x reference)
//
#include <hip/hip_runtime.h>
#include <hip/hip_bf16.h>

#define TOK_T 8
#define TOK_H 32
#define TOK_W 32
#define NTOK 8192      // tokens per batch
#define BATCH 2
#define DMODEL 256
#define D3 768
#define NHEADS 8
#define DHEAD 32

using short8  = __attribute__((ext_vector_type(8))) short;
using ushort8 = __attribute__((ext_vector_type(8))) unsigned short;
using f32x4   = __attribute__((ext_vector_type(4))) float;

__device__ __forceinline__ ushort f2bf(float f) {
  union { float f; unsigned u; } v; v.f = f;
  unsigned u = v.u;
  unsigned r = (u + 0x7FFFu + ((u >> 16) & 1u)) >> 16;
  return (ushort)r;
}
__device__ __forceinline__ float bf2f(ushort u) {
  union { unsigned u; float f; } v; v.u = ((unsigned)u) << 16;
  return v.f;
}

// ---------------- fused f32 -> bf16 conversion (one launch for all 3 arrays) ----------------
#define NX4  (BATCH * NTOK * DMODEL / 4)   // 1048576
#define NW14 (D3 * DMODEL / 4)             // 49152
#define NW24 (DMODEL * DMODEL / 4)         // 16384

__global__ __launch_bounds__(256) void convert_all(const float* __restrict__ x,
                                                   const float* __restrict__ wq,
                                                   const float* __restrict__ wo,
                                                   ushort* __restrict__ xb,
                                                   ushort* __restrict__ wqb,
                                                   ushort* __restrict__ wob) {
  int i = blockIdx.x * 256 + threadIdx.x;
  const float* src; ushort* dst; int j;
  if (i < NX4)              { src = x;  dst = xb;  j = i; }
  else if (i < NX4 + NW14)  { src = wq; dst = wqb; j = i - NX4; }
  else if (i < NX4 + NW14 + NW24) { src = wo; dst = wob; j = i - NX4 - NW14; }
  else return;
  float4 v = ((const float4*)src)[j];
  ushort4 o;
  o.x = f2bf(v.x); o.y = f2bf(v.y); o.z = f2bf(v.z); o.w = f2bf(v.w);
  ((ushort4*)dst)[j] = o;
}

// ---------------- bf16 GEMM, C = A[M,K] * B[N,K]^T ----------------
// TBM x TBN tile, BK=32, NW waves; each wave owns a 64x64 sub-tile
// (wr = wid / (TBN/64), wc = wid % (TBN/64)), mfma_f32_16x16x32_bf16.
// Double-buffered LDS: stage(t+1) issued before compute(t).
// Bank-conflict fix: slot swizzle k' = k ^ ((r>>1)&3) on BOTH global src and ds_read.
#define BKK 32

template<int TBM, int TBN, int NW, bool OUT_BF16>
__global__ __launch_bounds__(NW * 64) void gemm_bt(const ushort* __restrict__ A,
                                                   const ushort* __restrict__ B,
                                                   void* __restrict__ Cv,
                                                   int M, int N, int K) {
  __shared__ __align__(16) ushort sA[2][TBM * BKK];
  __shared__ __align__(16) ushort sB[2][TBN * BKK];
  constexpr int NCW = TBN / 64;     // waves along N
  constexpr int CHA = TBM * 4;      // 16B chunks in A tile
  constexpr int CHB = TBN * 4;
  constexpr int CH  = CHA + CHB;
  constexpr int NT  = NW * 64;

  const int tid  = threadIdx.x;
  const int lane = tid & 63;
  const int wid  = tid >> 6;
  const int wr   = wid / NCW;
  const int wc   = wid % NCW;
  const int bm   = blockIdx.x * TBM;
  const int bn   = blockIdx.y * TBN;
  const int fr   = lane & 15;
  const int kb   = lane >> 4;

  f32x4 acc[4][4] = {};

  auto stage = [&](int buf, int kt) {
#pragma unroll
    for (int c0 = 0; c0 < CH; c0 += NT) {
      int c  = c0 + tid;
      int cb = c - lane;               // wave-uniform chunk base
      // A/B split is wave-uniform: CHA is a multiple of 64
      bool isA = (c < CHA);
      int cc  = isA ? c  : c - CHA;
      int cbb = isA ? cb : cb - CHA;
      int r  = cc >> 2;
      int sl = cc & 3;
      int ss = sl ^ ((r >> 1) & 3);    // inverse-swizzled source slot
      const ushort* src = (isA ? A + (size_t)(bm + r) * K
                               : B + (size_t)(bn + r) * K) + kt + ss * 8;
      ushort* dst = isA ? &sA[buf][cbb * 8] : &sB[buf][cbb * 8];
      __builtin_amdgcn_global_load_lds((const __attribute__((address_space(1))) void*)src,
                                       (__attribute__((address_space(3))) void*)dst, 16, 0, 0);
    }
  };

  const int nit = K >> 5;
  stage(0, 0);
  __syncthreads();

  for (int it = 0; it < nit; ++it) {
    const int cur = it & 1;
    if (it + 1 < nit) stage(cur ^ 1, (it + 1) << 5);   // prefetch next tile

    short8 af[4], bfr[4];
#pragma unroll
    for (int m = 0; m < 4; ++m) {
      int r  = wr * 64 + m * 16 + fr;
      int ck = r * 4 + (kb ^ ((r >> 1) & 3));   // swizzled read
      af[m] = *(const short8*)&sA[cur][ck * 8];
    }
#pragma unroll
    for (int n = 0; n < 4; ++n) {
      int r  = wc * 64 + n * 16 + fr;
      int ck = r * 4 + (kb ^ ((r >> 1) & 3));
      bfr[n] = *(const short8*)&sB[cur][ck * 8];
    }
#pragma unroll
    for (int m = 0; m < 4; ++m)
#pragma unroll
      for (int n = 0; n < 4; ++n)
        acc[m][n] = __builtin_amdgcn_mfma_f32_16x16x32_bf16(af[m], bfr[n], acc[m][n], 0, 0, 0);
    __syncthreads();   // drains vmcnt(0): next buffer staged and safe
  }

  // epilogue: C/D layout col=lane&15, row=(lane>>4)*4+j
  if constexpr (OUT_BF16) {
    ushort* C = (ushort*)Cv;
#pragma unroll
    for (int m = 0; m < 4; ++m)
#pragma unroll
      for (int n = 0; n < 4; ++n)
#pragma unroll
        for (int j = 0; j < 4; ++j) {
          int row = bm + wr * 64 + m * 16 + kb * 4 + j;
          int col = bn + wc * 64 + n * 16 + fr;
          C[(size_t)row * N + col] = f2bf(acc[m][n][j]);
        }
  } else {
    float* C = (float*)Cv;
#pragma unroll
    for (int m = 0; m < 4; ++m)
#pragma unroll
      for (int n = 0; n < 4; ++n)
#pragma unroll
        for (int j = 0; j < 4; ++j) {
          int row = bm + wr * 64 + m * 16 + kb * 4 + j;
          int col = bn + wc * 64 + n * 16 + fr;
          C[(size_t)row * N + col] = acc[m][n][j];
        }
  }
}

// ---------------- local attention ----------------
// One block per (batch, head, 4x8x8 spatial tile); 256 threads = 1 token each.
// Halo 6x10x10 = 600 tokens. ONE 48KB LDS buffer reused: stage K -> scores ->
// barrier -> stage V -> PV. KP=40 ushorts (80B rows): b128 reads land uniform
// across all 32 banks (8 lanes per 16B slot-position = minimum for wave64 b128).
#define TT 4
#define TLH 8
#define TLW 8
#define NHALO 600
#define KP 40

__global__ __launch_bounds__(256) void local_attn(const ushort* __restrict__ qkv,
                                                  ushort* __restrict__ aob) {
  __shared__ __align__(16) ushort sh[NHALO * KP];   // 48000 B, reused for K then V
  const int tile = blockIdx.x;   // 0..31
  const int head = blockIdx.y;   // 0..7
  const int b    = blockIdx.z;   // 0..1
  const int tz = tile >> 4;      // 0..1  (8/TT = 2 along T)
  const int ty = (tile >> 2) & 3;
  const int tx = tile & 3;
  const int t0 = tz * TT, h0 = ty * TLH, w0 = tx * TLW;
  const int tid = threadIdx.x;

  auto stage = [&](int ofs) {   // ofs = DMODEL for K, 2*DMODEL for V
    for (int idx = tid; idx < NHALO; idx += 256) {
      int ht  = idx / 100;
      int rem = idx - ht * 100;
      int hh  = rem / 10;
      int hw  = rem - hh * 10;
      int gt = t0 - 1 + ht, gh = h0 - 1 + hh, gw = w0 - 1 + hw;
      ushort8* dst = (ushort8*)&sh[idx * KP];
      if (gt >= 0 && gt < TOK_T && gh >= 0 && gh < TOK_H && gw >= 0 && gw < TOK_W) {
        size_t base = ((size_t)b * NTOK + (size_t)gt * 1024 + gh * 32 + gw) * D3;
        const ushort8* s = (const ushort8*)(qkv + base + ofs + head * DHEAD);
#pragma unroll
        for (int p = 0; p < 4; ++p) dst[p] = s[p];
      } else {
        ushort8 z = (ushort8)0;
#pragma unroll
        for (int p = 0; p < 4; ++p) dst[p] = z;
      }
    }
  };

  // ---- stage K ----
  stage(DMODEL);

  const int tt = tid >> 6;       // 0..3
  const int th = (tid >> 3) & 7;
  const int tw = tid & 7;
  const int n  = (t0 + tt) * 1024 + (h0 + th) * 32 + (w0 + tw);

  // q in registers (global read overlaps K staging latency-wise)
  const ushort* qp = qkv + ((size_t)b * NTOK + n) * D3 + head * DHEAD;
  float q[DHEAD];
  {
    const ushort8* qs = (const ushort8*)qp;
#pragma unroll
    for (int p = 0; p < 4; ++p) {
      ushort8 v = qs[p];
#pragma unroll
      for (int e = 0; e < 8; ++e) q[p * 8 + e] = bf2f(v[e]);
    }
  }
  __syncthreads();

  // ---- scores ----
  const float scale = 0.1767766952966369f;  // 1/sqrt(32)
  float s[27];
#pragma unroll
  for (int nb = 0; nb < 27; ++nb) {
    int dt = nb / 9, dh = (nb / 3) % 3, dw = nb % 3;
    int hidx = (tt + dt) * 100 + (th + dh) * 10 + (tw + dw);
    const ushort8* kp = (const ushort8*)&sh[hidx * KP];
    float a = 0.f;
#pragma unroll
    for (int p = 0; p < 4; ++p) {
      ushort8 kk = kp[p];
#pragma unroll
      for (int e = 0; e < 8; ++e) a += q[p * 8 + e] * bf2f(kk[e]);
    }
    s[nb] = a * scale;
  }
  __syncthreads();   // all K reads done before V overwrites

  // ---- stage V (same buffer) ----
  stage(2 * DMODEL);

  float mx = s[0];
#pragma unroll
  for (int nb = 1; nb < 27; ++nb) mx = fmaxf(mx, s[nb]);
  __syncthreads();

  // ---- softmax + PV ----
  float o[DHEAD] = {};
  float sum = 0.f;
#pragma unroll
  for (int nb = 0; nb < 27; ++nb) {
    int dt = nb / 9, dh = (nb / 3) % 3, dw = nb % 3;
    int hidx = (tt + dt) * 100 + (th + dh) * 10 + (tw + dw);
    const ushort8* vp = (const ushort8*)&sh[hidx * KP];
    float p = __expf(s[nb] - mx);
    sum += p;
#pragma unroll
    for (int c = 0; c < 4; ++c) {
      ushort8 vv = vp[c];
#pragma unroll
      for (int e = 0; e < 8; ++e) o[c * 8 + e] += p * bf2f(vv[e]);
    }
  }

  float inv = 1.f / sum;
  ushort8 os[4];
#pragma unroll
  for (int c = 0; c < 4; ++c)
#pragma unroll
    for (int e = 0; e < 8; ++e) os[c][e] = f2bf(o[c * 8 + e] * inv);
  ushort8* op = (ushort8*)(aob + ((size_t)b * NTOK + n) * DMODEL + head * DHEAD);
#pragma unroll
  for (int c = 0; c < 4; ++c) op[c] = os[c];
}

// ---------------- launch ----------------
extern "C" void kernel_launch(void* const* d_in, const int* in_sizes, int n_in,
                              void* d_out, int out_size, void* d_ws, size_t ws_size,
                              hipStream_t stream) {
  const float* x     = (const float*)d_in[0];
  const float* w_qkv = (const float*)d_in[1];
  const float* w_out = (const float*)d_in[2];
  float* out = (float*)d_out;

  char* ws = (char*)d_ws;
  size_t off = 0;
  ushort* xb    = (ushort*)(ws + off); off += (size_t)BATCH * NTOK * DMODEL * 2;  // 8 MB
  ushort* wqkvb = (ushort*)(ws + off); off += (size_t)D3 * DMODEL * 2;
  ushort* woutb = (ushort*)(ws + off); off += (size_t)DMODEL * DMODEL * 2;
  ushort* qkvb  = (ushort*)(ws + off); off += (size_t)BATCH * NTOK * D3 * 2;      // 24 MB
  ushort* aob   = (ushort*)(ws + off); off += (size_t)BATCH * NTOK * DMODEL * 2;  // 8 MB

  int ntot = NX4 + NW14 + NW24;
  convert_all<<<(ntot + 255) / 256, 256, 0, stream>>>(x, w_qkv, w_out, xb, wqkvb, woutb);

  // GEMM1: [16384 x 256] x [768 x 256]^T, 128x256 tile, 8 waves -> A re-read only 3x
  dim3 g1(BATCH * NTOK / 128, D3 / 256);   // 128 x 3
  gemm_bt<128, 256, 8, true><<<g1, 512, 0, stream>>>(xb, wqkvb, (void*)qkvb,
                                                     BATCH * NTOK, D3, DMODEL);

  // attention: 32 tiles x 8 heads x 2 batch, 256 threads
  dim3 ga(32, NHEADS, BATCH);
  local_attn<<<ga, 256, 0, stream>>>(qkvb, aob);

  // GEMM2: [16384 x 256] x [256 x 256]^T, 64x256 tile, 4 waves -> aob read once, grid 256
  dim3 g2(BATCH * NTOK / 64, DMODEL / 256);  // 256 x 1
  gemm_bt<64, 256, 4, false><<<g2, 256, 0, stream>>>(aob, woutb, (void*)out,
                                                     BATCH * NTOK, DMODEL, DMODEL);
}